// Round 4
// baseline (223.669 us; speedup 1.0000x reference)
//
#include <hip/hip_runtime.h>

#define STEPS 10
#define EPB 64                 // elements per block
#define SLAB_FLOATS 384        // 64 elem * 6 floats
#define LDS_FLOATS 5120        // 20 chunks * 1024 B = 20480 B

#define GLOAD_LDS16(gp, lp)                                            \
    __builtin_amdgcn_global_load_lds(                                  \
        (const __attribute__((address_space(1))) void*)(gp),           \
        (__attribute__((address_space(3))) void*)(lp), 16, 0, 0)

__global__ __launch_bounds__(256) void spiking_vestibular_kernel(
    const float* __restrict__ speed,
    const float* __restrict__ turn_rate,
    const float* __restrict__ predicted_turn,
    const float* __restrict__ predicted_speed,
    const float* __restrict__ noise,
    const float* __restrict__ v0,
    const float* __restrict__ u0,
    const float* __restrict__ rate0,
    float* __restrict__ out,
    int B)
{
#pragma clang fp contract(off)
    __shared__ float smem[LDS_FLOATS];

    const int tid  = threadIdx.x;
    const int wave = tid >> 6;
    const int lane = tid & 63;
    const long long b0 = (long long)blockIdx.x * EPB;

    const long long nz_lim = (long long)STEPS * B * 6 - 4; // last valid f4 start
    const long long st_lim = (long long)B * 6 - 4;

    // ---- stage 13 slabs (1536 B each, slab-linear in LDS) via 16B async DMA
    // flat f4 index k = chunk*64 + lane; LDS dest = chunk*1024 + lane*16
    // (wave-uniform base; HW adds lane*16); global source per-lane computed.
#pragma unroll
    for (int r = 0; r < 5; ++r) {
        const int c = r * 4 + wave;              // chunk 0..19
        const int k = (c << 6) | lane;           // 0..1279
        int s = k / 96;                          // slab 0..13
        const int off16 = k - s * 96;            // f4 within slab
        if (s > 12) s = 0;                       // pad chunk: harmless dup
        const float* basep;
        long long fidx, lim;
        if (s < 10)       { basep = noise; fidx = ((long long)s * B + b0) * 6; lim = nz_lim; }
        else if (s == 10) { basep = v0;    fidx = b0 * 6; lim = st_lim; }
        else if (s == 11) { basep = u0;    fidx = b0 * 6; lim = st_lim; }
        else              { basep = rate0; fidx = b0 * 6; lim = st_lim; }
        fidx += (long long)off16 * 4;
        if (fidx > lim) fidx = lim;              // tail-block clamp (16B aligned)
        GLOAD_LDS16(basep + fidx, &smem[c * 256]);
    }

    __syncthreads();   // drains vmcnt before barrier

    // ---- compute: 4 lanes per element; lane g<3 owns neurons {2g,2g+1} ----
    const int e = tid >> 2;                      // local element 0..63
    const int g = tid & 3;
    const long long b = b0 + e;
    if (b >= B) return;                          // after the only barrier: safe

    const int goff = (g == 3) ? 0 : (2 * g);
    const int sb = e * 6 + goff;

    float2 nzv[STEPS];
#pragma unroll
    for (int t = 0; t < STEPS; ++t)
        nzv[t] = *reinterpret_cast<const float2*>(&smem[t * SLAB_FLOATS + sb]);
    float2 v2 = *reinterpret_cast<const float2*>(&smem[10 * SLAB_FLOATS + sb]);
    float2 u2 = *reinterpret_cast<const float2*>(&smem[11 * SLAB_FLOATS + sb]);
    float2 r2 = *reinterpret_cast<const float2*>(&smem[12 * SLAB_FLOATS + sb]);

    float tr = turn_rate[b];
    float sp = speed[b];
    float pt = predicted_turn[b];
    float ps = predicted_speed[b];

    float tilt = fminf(1.0f, (fabsf(tr) * sp) * 0.5f);

    float t8 = tilt * 8.0f;
    float Ia = (g == 0) ? fmaxf(0.0f, tr) * 10.0f
             : (g == 1) ? sp * 5.0f
             : t8;
    float Ib = (g == 0) ? fmaxf(0.0f, -tr) * 10.0f
             : (g == 1) ? fmaxf(0.0f, -sp + 0.5f) * 5.0f
             : t8;

    float va = v2.x, vb = v2.y;
    float ua = u2.x, ub = u2.y;
    float ra = r2.x, rb = r2.y;

#pragma unroll
    for (int t = 0; t < STEPS; ++t) {
        {   // neuron A = 2g
            float i_tot = Ia + nzv[t].x * 0.3f + (-1.0f);
            float vv = va, un = ua;
            vv = vv + (((((0.04f * vv) * vv) + (5.0f * vv)) + 140.0f) - un + i_tot);
            un = un + 0.02f * ((0.2f * vv) - un);
            bool fired = (vv >= 30.0f);
            float spk = fired ? 1.0f : 0.0f;
            vv = fired ? -65.0f : vv;
            un = un + spk * 8.0f;
            ra = ra * 0.9f + spk * 0.1f;
            va = vv; ua = un;
        }
        {   // neuron B = 2g+1
            float i_tot = Ib + nzv[t].y * 0.3f + (-1.0f);
            float vv = vb, un = ub;
            vv = vv + (((((0.04f * vv) * vv) + (5.0f * vv)) + 140.0f) - un + i_tot);
            un = un + 0.02f * ((0.2f * vv) - un);
            bool fired = (vv >= 30.0f);
            float spk = fired ? 1.0f : 0.0f;
            vv = fired ? -65.0f : vv;
            un = un + spk * 8.0f;
            rb = rb * 0.9f + spk * 0.1f;
            vb = vv; ub = un;
        }
    }

    float s  = ra + rb;
    float s1 = __shfl_down(s, 1, 4);
    float s2 = __shfl_down(s, 2, 4);
    float rate_mean = ((s + s1) + s2) / 6.0f;

    // ---- TwoCompColumn relaxation (redundant per lane, cheap) ----
    float cb0 = 0.0f, cb1 = 0.0f, ca0 = 0.0f, ca1 = 0.0f;
#pragma unroll
    for (int k2 = 0; k2 < 8; ++k2) {
        cb0 = cb0 + 0.5f * (tr - cb0);
        cb1 = cb1 + 0.5f * (sp - cb1);
        ca0 = ca0 + 0.5f * (pt - ca0);
        ca1 = ca1 + 0.5f * (ps - ca1);
    }
    float pe0 = cb0 - ca0;
    float pe1 = cb1 - ca1;
    float prec0 = 1.0f / (1.0f + pe0 * pe0);
    float prec1 = 1.0f / (1.0f + pe1 * pe1);
    float fe = 0.5f * (((prec0 * pe0) * pe0) + ((prec1 * pe1) * pe1));
    float pe_w = 0.7f * pe0 + 0.3f * pe1;
    float prec_mean = (prec0 + prec1) / 2.0f;
    float postural = (-prec_mean) * pe_w * 0.3f;

    if (g < 3) {
        float2 o = (g == 0) ? make_float2(tilt, rate_mean)
                 : (g == 1) ? make_float2(postural, pe_w)
                 :            make_float2(prec_mean, fe);
        *reinterpret_cast<float2*>(out + (size_t)b * 6 + 2 * g) = o;
    }
}

extern "C" void kernel_launch(void* const* d_in, const int* in_sizes, int n_in,
                              void* d_out, int out_size, void* d_ws, size_t ws_size,
                              hipStream_t stream) {
    // setup_inputs order:
    // 0 heading (unused), 1 speed, 2 turn_rate, 3 predicted_turn,
    // 4 predicted_speed, 5 noise [STEPS,B,N], 6 v0, 7 u0, 8 rate0
    const float* speed           = (const float*)d_in[1];
    const float* turn_rate       = (const float*)d_in[2];
    const float* predicted_turn  = (const float*)d_in[3];
    const float* predicted_speed = (const float*)d_in[4];
    const float* noise           = (const float*)d_in[5];
    const float* v0              = (const float*)d_in[6];
    const float* u0              = (const float*)d_in[7];
    const float* rate0           = (const float*)d_in[8];
    float* out                   = (float*)d_out;

    int B = in_sizes[1];
    int grid = (B + EPB - 1) / EPB;
    spiking_vestibular_kernel<<<grid, 256, 0, stream>>>(
        speed, turn_rate, predicted_turn, predicted_speed,
        noise, v0, u0, rate0, out, B);
}